// Round 11
// baseline (170.323 us; speedup 1.0000x reference)
//
#include <hip/hip_runtime.h>
#include <hip/hip_bf16.h>

typedef __attribute__((ext_vector_type(8))) short bf16x8;
typedef __attribute__((ext_vector_type(16))) float f32x16;
typedef __attribute__((ext_vector_type(4))) unsigned u32x4;

#define TH 0.01f
#define MFMA32(a, b, c) __builtin_amdgcn_mfma_f32_32x32x16_bf16(a, b, c, 0, 0, 0)

constexpr int D = 512, F = 2048, BM = 128, NC = 64;  // FC=32 hcols/chunk

// LDS map (163840 B = full 160 KiB)
constexpr int W1A_O = 0;        // w1 chunk slot 0          32 KB
constexpr int W1B_O = 32768;    // w1 chunk slot 1          32 KB
constexpr int W2A_O = 65536;    // w2 chunk slot 0          32 KB  (x slab in
constexpr int W2B_O = 98304;    // w2 chunk slot 1          32 KB   prologue)
constexpr int H2_0  = 131072;   // h buf 0 [4][128][8]bf16   8 KB  (spike tmp
constexpr int H2_1  = 139264;   // h buf 1                   8 KB   in prologue)
constexpr int HP_O  = 147456;   // bf16 partials [4][64][16] 8 KB
constexpr int B1_O  = 155648;   // b1 f32[2048]              8 KB
constexpr int LDS_TOTAL = 163840;

static __device__ __forceinline__ short f2bf(float f) {
  union { float f; unsigned u; } v; v.f = f;
  unsigned r = v.u + 0x7FFFu + ((v.u >> 16) & 1u);  // RNE
  return (short)(r >> 16);
}

static __device__ __forceinline__ void gl16(const void* g, char* l) {
  __builtin_amdgcn_global_load_lds(
      (const __attribute__((address_space(1))) unsigned*)g,
      (__attribute__((address_space(3))) unsigned*)l, 16, 0, 0);
}

// ---------------------------------------------------------------------------
// Fragment-major staged layouts (32x32x16 MFMA; A/B frag: lane l: idx=l&31,
// k = 8*(l>>5)+j). Every main-loop weight ds_read is LINEAR in lane.
// w1s: 64 regions (chunk c) x 32KB: granule g: ks=g>>6 (0..31), lane=g&63;
//      elems j: w1[ks*16 + (lane>>5)*8 + j][c*32 + (lane&31)]
// w2s: 64 regions x 32KB: granule g: ks=g>>10 (0..1), cf=(g>>6)&15, lane=g&63;
//      elems j: w2[c*32 + ks*16 + (lane>>5)*8 + j][cf*32 + (lane&31)]
// ---------------------------------------------------------------------------
__global__ void prep_weights(const float* __restrict__ w1, const float* __restrict__ w2,
                             short* __restrict__ w1s, short* __restrict__ w2s) {
  int G = blockIdx.x * 256 + threadIdx.x;
  if (G < 131072) {
    int c = G >> 11, g = G & 2047;
    int ks = g >> 6, lane = g & 63, l31 = lane & 31, l5 = lane >> 5;
    bf16x8 v;
#pragma unroll
    for (int j = 0; j < 8; ++j)
      v[j] = f2bf(w1[(size_t)(ks * 16 + l5 * 8 + j) * F + c * 32 + l31]);
    *(bf16x8*)(w1s + (size_t)G * 8) = v;
  } else {
    int H = G - 131072;
    int c = H >> 11, g = H & 2047;
    int ks = g >> 10, cf = (g >> 6) & 15, lane = g & 63, l31 = lane & 31, l5 = lane >> 5;
    bf16x8 v;
#pragma unroll
    for (int j = 0; j < 8; ++j)
      v[j] = f2bf(w2[(size_t)(c * 32 + ks * 16 + l5 * 8 + j) * D + cf * 32 + l31]);
    *(bf16x8*)(w2s + (size_t)H * 8) = v;
  }
}

// all 512 threads stage one 32KB slot: 4 x 16B granules per thread.
#define ISSUE4(loff, gptr)                                                      \
  do {                                                                          \
    _Pragma("unroll") for (int _t = 0; _t < 4; ++_t)                            \
        gl16((const char*)(gptr) + (size_t)(_t * 512 + tid) * 16,               \
             smem + (loff) + (_t * 512 + tid) * 16);                            \
  } while (0)

__global__ __launch_bounds__(512, 2)
void ffn_fused(const float* __restrict__ x,
               const float* __restrict__ b1,
               const float* __restrict__ b2,
               const char* __restrict__ w1g,
               const char* __restrict__ w2g,
               float* __restrict__ out) {
  extern __shared__ char smem[];
  const int tid = threadIdx.x;
  const int lane = tid & 63, wid = tid >> 6;
  const int l31 = lane & 31, l5 = lane >> 5;
  const int row0 = blockIdx.x * BM;

  // SIMD-balanced roles: SIMD s hosts waves {s, s+4} = pair p=s with both
  // k-halves -> PH2 combine (kh0) occupies exactly one wave per SIMD.
  const int p  = wid & 3,  kh = wid >> 2;  // G1: pair (32 rows), k-half
  const int cq = wid & 3,  rh = wid >> 2;  // G2: col-quad (128), row-half (64)
  unsigned* tmpspk = (unsigned*)(smem + H2_0);  // prologue-only

  // ---------------- prologue ----------------
  if (tid < 4) tmpspk[tid] = 0u;
  ISSUE4(W1A_O, w1g);  // w1 chunk 0 -> slot 0
  *(float4*)((float*)(smem + B1_O) + tid * 4) = *(const float4*)&b1[tid * 4];

  // x rows -> swizzled f32 slab (W2 slots, free now) -> pair-half regs.
  bf16x8 xr[16];
  for (int r = 0; r < 4; ++r) {
    {
      const float* xg = x + (size_t)(row0 + r * 32) * D;
      float* xs = (float*)(smem + W2A_O);
#pragma unroll
      for (int it = 0; it < 8; ++it) {
        int idx = it * 512 + tid;
        int rl = idx >> 7, col = (idx & 127) * 4;
        float4 v = *(const float4*)(xg + rl * 512 + col);
        *(float4*)(xs + rl * 512 + (col ^ ((rl & 7) << 2))) = v;
      }
    }
    asm volatile("s_waitcnt vmcnt(0) lgkmcnt(0)" ::: "memory");
    __builtin_amdgcn_s_barrier();
    if (p == r) {  // pair r: both k-half waves extract their 16 frags
      const float* xs = (const float*)(smem + W2A_O);
      bool rowany = false;
#pragma unroll
      for (int s = 0; s < 16; ++s) {
        int base = kh * 256 + s * 16 + l5 * 8;
        int c0 = base ^ ((l31 & 7) << 2);
        int c1 = (base + 4) ^ ((l31 & 7) << 2);
        float4 a4 = *(const float4*)(xs + l31 * 512 + c0);
        float4 b4 = *(const float4*)(xs + l31 * 512 + c1);
        rowany = rowany | (fabsf(a4.x) > TH) | (fabsf(a4.y) > TH) |
                 (fabsf(a4.z) > TH) | (fabsf(a4.w) > TH) | (fabsf(b4.x) > TH) |
                 (fabsf(b4.y) > TH) | (fabsf(b4.z) > TH) | (fabsf(b4.w) > TH);
        bf16x8 t;
        t[0] = f2bf(a4.x); t[1] = f2bf(a4.y); t[2] = f2bf(a4.z); t[3] = f2bf(a4.w);
        t[4] = f2bf(b4.x); t[5] = f2bf(b4.y); t[6] = f2bf(b4.z); t[7] = f2bf(b4.w);
        xr[s] = t;
      }
      unsigned long long bl = __ballot(rowany);  // bit l = row (l&31) any
      if (lane == 0) atomicOr(&tmpspk[r], (unsigned)bl | (unsigned)(bl >> 32));
    }
    asm volatile("s_waitcnt lgkmcnt(0)" ::: "memory");
    __builtin_amdgcn_s_barrier();
  }
  // spike masks for this wave's G2 rows (rh*64 .. +63) -> 2 regs
  const unsigned smv0 = tmpspk[rh * 2 + 0];
  const unsigned smv1 = tmpspk[rh * 2 + 1];
  asm volatile("s_waitcnt vmcnt(0) lgkmcnt(0)" ::: "memory");
  __builtin_amdgcn_s_barrier();  // w1[0] landed; H2_0 free

  f32x16 oacc[8];
#pragma unroll
  for (int n = 0; n < 8; ++n)
#pragma unroll
    for (int j = 0; j < 16; ++j) oacc[n][j] = 0.f;

  const float* b1s = (const float*)(smem + B1_O);

  // ------------- main loop: 64 chunks x {PH1 (heavy), PH2 (short)} -------
  // PH1(i): issue w2[i]->slot[i&1], w1[i+1]->slot[(i+1)&1];
  //         G2(i-1)  [slot (i-1)&1 drained @end-PH2(i-1); h2 via barrier];
  //         vmcnt(8) [drains w1[i], oldest 4 of 12];
  //         G1(i); kh1: pack partials -> hp.       end: lgkm + barrier.
  // PH2(i): kh0: combine hp + bias + relu -> h2[i&1].
  //         end: vmcnt(4) [drains w2[i], keeps w1[i+1]] + barrier.
#pragma unroll 1
  for (int i = 0; i < NC; ++i) {
    const int sl = i & 1;
    // ---- PH1 ----
    ISSUE4(sl ? W2B_O : W2A_O, w2g + (size_t)i * 32768);
    if (i < NC - 1) ISSUE4(sl ? W1A_O : W1B_O, w1g + (size_t)(i + 1) * 32768);

    if (i > 0) {  // G2 on chunk i-1 (pure-LDS deps, starts immediately)
      const int js = (i - 1) & 1;
      const char* h2r  = smem + (js ? H2_1 : H2_0);
      const char* w2rd = smem + (js ? W2B_O : W2A_O);
      __builtin_amdgcn_s_setprio(1);
#pragma unroll
      for (int ks = 0; ks < 2; ++ks) {
        bf16x8 hA0 = *(const bf16x8*)(h2r + ((2 * ks + l5) * 128 + rh * 64 + l31) * 16);
        bf16x8 hA1 = *(const bf16x8*)(h2r + ((2 * ks + l5) * 128 + rh * 64 + 32 + l31) * 16);
#pragma unroll
        for (int n = 0; n < 4; ++n) {
          bf16x8 wf = *(const bf16x8*)(w2rd + ks * 16384 + (cq * 4 + n) * 1024 + lane * 16);
          oacc[n]     = MFMA32(hA0, wf, oacc[n]);
          oacc[4 + n] = MFMA32(hA1, wf, oacc[4 + n]);
        }
      }
      __builtin_amdgcn_s_setprio(0);
    }

    if (i < NC - 1) asm volatile("s_waitcnt vmcnt(8)" ::: "memory");
    else            asm volatile("s_waitcnt vmcnt(4)" ::: "memory");

    {  // G1 on chunk i
      const char* w1slot = smem + (sl ? W1B_O : W1A_O);
      f32x16 hacc;
#pragma unroll
      for (int j = 0; j < 16; ++j) hacc[j] = 0.f;
      __builtin_amdgcn_s_setprio(1);
#pragma unroll
      for (int s = 0; s < 16; ++s) {
        bf16x8 wf = *(const bf16x8*)(w1slot + (kh * 16 + s) * 1024 + lane * 16);
        hacc = MFMA32(wf, xr[s], hacc);
      }
      __builtin_amdgcn_s_setprio(0);
      if (kh) {  // odd k-half: bf16-pack partial -> hp
        u32x4 pk0, pk1;
#pragma unroll
        for (int t = 0; t < 4; ++t) {
          pk0[t] = (unsigned)(unsigned short)f2bf(hacc[2 * t]) |
                   ((unsigned)(unsigned short)f2bf(hacc[2 * t + 1]) << 16);
          pk1[t] = (unsigned)(unsigned short)f2bf(hacc[8 + 2 * t]) |
                   ((unsigned)(unsigned short)f2bf(hacc[8 + 2 * t + 1]) << 16);
        }
        *(u32x4*)(smem + HP_O + p * 2048 + lane * 32) = pk0;
        *(u32x4*)(smem + HP_O + p * 2048 + lane * 32 + 16) = pk1;
      }
      asm volatile("s_waitcnt lgkmcnt(0)" ::: "memory");
      __builtin_amdgcn_s_barrier();  // end-PH1

      // ---- PH2 ----
      if (!kh) {  // even k-half: combine + bias + relu + pack -> h2[sl]
        const char* hp = smem + HP_O + p * 2048;
        u32x4 q0 = *(const u32x4*)(hp + lane * 32);
        u32x4 q1 = *(const u32x4*)(hp + lane * 32 + 16);
#pragma unroll
        for (int t = 0; t < 4; ++t) {
          hacc[2 * t]     += __uint_as_float(q0[t] << 16);
          hacc[2 * t + 1] += __uint_as_float(q0[t] & 0xffff0000u);
          hacc[8 + 2 * t]     += __uint_as_float(q1[t] << 16);
          hacc[8 + 2 * t + 1] += __uint_as_float(q1[t] & 0xffff0000u);
        }
        char* h2w = smem + (sl ? H2_1 : H2_0);
#pragma unroll
        for (int q = 0; q < 4; ++q) {
          float4 bv = *(const float4*)&b1s[i * 32 + q * 8 + l5 * 4];
          short4 pk;
          pk.x = f2bf(fmaxf(hacc[4 * q + 0] + bv.x, 0.f));
          pk.y = f2bf(fmaxf(hacc[4 * q + 1] + bv.y, 0.f));
          pk.z = f2bf(fmaxf(hacc[4 * q + 2] + bv.z, 0.f));
          pk.w = f2bf(fmaxf(hacc[4 * q + 3] + bv.w, 0.f));
          *(short4*)(h2w + q * 2048 + (p * 32 + l31) * 16 + l5 * 8) = pk;
        }
      }
    }
    if (i < NC - 1) asm volatile("s_waitcnt vmcnt(4) lgkmcnt(0)" ::: "memory");
    else            asm volatile("s_waitcnt vmcnt(0) lgkmcnt(0)" ::: "memory");
    __builtin_amdgcn_s_barrier();  // end-PH2
  }

  // ---------------- epilogue: G2 chunk 63 + store ----------------
  {
    const char* h2r  = smem + H2_1;   // 63 & 1 = 1
    const char* w2rd = smem + W2B_O;
    __builtin_amdgcn_s_setprio(1);
#pragma unroll
    for (int ks = 0; ks < 2; ++ks) {
      bf16x8 hA0 = *(const bf16x8*)(h2r + ((2 * ks + l5) * 128 + rh * 64 + l31) * 16);
      bf16x8 hA1 = *(const bf16x8*)(h2r + ((2 * ks + l5) * 128 + rh * 64 + 32 + l31) * 16);
#pragma unroll
      for (int n = 0; n < 4; ++n) {
        bf16x8 wf = *(const bf16x8*)(w2rd + ks * 16384 + (cq * 4 + n) * 1024 + lane * 16);
        oacc[n]     = MFMA32(hA0, wf, oacc[n]);
        oacc[4 + n] = MFMA32(hA1, wf, oacc[4 + n]);
      }
    }
    __builtin_amdgcn_s_setprio(0);
  }
#pragma unroll
  for (int rfi = 0; rfi < 2; ++rfi) {
    unsigned m = rfi ? smv1 : smv0;
#pragma unroll
    for (int n = 0; n < 4; ++n) {
      int dcol = cq * 128 + n * 32 + l31;
      float bias = b2[dcol];
      f32x16 acc = oacc[rfi * 4 + n];
#pragma unroll
      for (int r = 0; r < 16; ++r) {
        int rbit = (r & 3) + 8 * (r >> 2) + 4 * l5;
        int row = rh * 64 + rfi * 32 + rbit;
        float v = acc[r] + bias;
        out[(size_t)(row0 + row) * D + dcol] = ((m >> rbit) & 1u) ? v : 0.f;
      }
    }
  }
}

extern "C" void kernel_launch(void* const* d_in, const int* in_sizes, int n_in,
                              void* d_out, int out_size, void* d_ws, size_t ws_size,
                              hipStream_t stream) {
  const float* x  = (const float*)d_in[0];
  const float* w1 = (const float*)d_in[1];
  const float* b1 = (const float*)d_in[2];
  const float* w2 = (const float*)d_in[3];
  const float* b2 = (const float*)d_in[4];
  float* out = (float*)d_out;

  short* w1staged = (short*)d_ws;               // 2 MB
  short* w2staged = w1staged + (size_t)D * F;   // 2 MB

  prep_weights<<<1024, 256, 0, stream>>>(w1, w2, w1staged, w2staged);

  (void)hipFuncSetAttribute((const void*)ffn_fused,
                            hipFuncAttributeMaxDynamicSharedMemorySize, LDS_TOTAL);
  int M = out_size / D;  // 32768
  ffn_fused<<<M / BM, 512, LDS_TOTAL, stream>>>(x, b1, b2, (const char*)w1staged,
                                                (const char*)w2staged, out);
}

// Round 12
// 164.466 us; speedup vs baseline: 1.0356x; 1.0356x over previous
//
#include <hip/hip_runtime.h>
#include <hip/hip_bf16.h>

typedef __attribute__((ext_vector_type(8))) short bf16x8;
typedef __attribute__((ext_vector_type(16))) float f32x16;
typedef __attribute__((ext_vector_type(4))) unsigned u32x4;

#define TH 0.01f
#define MFMA32(a, b, c) __builtin_amdgcn_mfma_f32_32x32x16_bf16(a, b, c, 0, 0, 0)

constexpr int D = 512, F = 2048, BM = 128, NC = 64;  // FC=32 hcols/chunk

// LDS map (163840 B = full 160 KiB)
constexpr int W1A_O = 0;        // w1 chunk slot 0          32 KB
constexpr int W1B_O = 32768;    // w1 chunk slot 1          32 KB
constexpr int W2A_O = 65536;    // w2 chunk slot 0          32 KB  (x slab in
constexpr int W2B_O = 98304;    // w2 chunk slot 1          32 KB   prologue)
constexpr int H2_0  = 131072;   // h buf 0 [4][128][8]bf16   8 KB  (spike tmp
constexpr int H2_1  = 139264;   // h buf 1                   8 KB   in prologue)
constexpr int HP_O  = 147456;   // bf16 partials [4][64][16] 8 KB
constexpr int B1_O  = 155648;   // b1 f32[2048]              8 KB
constexpr int LDS_TOTAL = 163840;

static __device__ __forceinline__ short f2bf(float f) {
  union { float f; unsigned u; } v; v.f = f;
  unsigned r = v.u + 0x7FFFu + ((v.u >> 16) & 1u);  // RNE
  return (short)(r >> 16);
}

static __device__ __forceinline__ void gl16(const void* g, char* l) {
  __builtin_amdgcn_global_load_lds(
      (const __attribute__((address_space(1))) unsigned*)g,
      (__attribute__((address_space(3))) unsigned*)l, 16, 0, 0);
}

// ---------------------------------------------------------------------------
// Fragment-major staged layouts (32x32x16 MFMA; A/B frag: lane l: idx=l&31,
// k = 8*(l>>5)+j). Every main-loop weight ds_read is LINEAR in lane.
// w1s: 64 regions (chunk c) x 32KB: granule g: ks=g>>6 (0..31), lane=g&63;
//      elems j: w1[ks*16 + (lane>>5)*8 + j][c*32 + (lane&31)]
// w2s: 64 regions x 32KB: granule g: ks=g>>10 (0..1), cf=(g>>6)&15, lane=g&63;
//      elems j: w2[c*32 + ks*16 + (lane>>5)*8 + j][cf*32 + (lane&31)]
// ---------------------------------------------------------------------------
__global__ void prep_weights(const float* __restrict__ w1, const float* __restrict__ w2,
                             short* __restrict__ w1s, short* __restrict__ w2s) {
  int G = blockIdx.x * 256 + threadIdx.x;
  if (G < 131072) {
    int c = G >> 11, g = G & 2047;
    int ks = g >> 6, lane = g & 63, l31 = lane & 31, l5 = lane >> 5;
    bf16x8 v;
#pragma unroll
    for (int j = 0; j < 8; ++j)
      v[j] = f2bf(w1[(size_t)(ks * 16 + l5 * 8 + j) * F + c * 32 + l31]);
    *(bf16x8*)(w1s + (size_t)G * 8) = v;
  } else {
    int H = G - 131072;
    int c = H >> 11, g = H & 2047;
    int ks = g >> 10, cf = (g >> 6) & 15, lane = g & 63, l31 = lane & 31, l5 = lane >> 5;
    bf16x8 v;
#pragma unroll
    for (int j = 0; j < 8; ++j)
      v[j] = f2bf(w2[(size_t)(c * 32 + ks * 16 + l5 * 8 + j) * D + cf * 32 + l31]);
    *(bf16x8*)(w2s + (size_t)H * 8) = v;
  }
}

// all 512 threads stage one 32KB slot: 4 x 16B granules per thread.
#define ISSUE4(loff, gptr)                                                      \
  do {                                                                          \
    _Pragma("unroll") for (int _t = 0; _t < 4; ++_t)                            \
        gl16((const char*)(gptr) + (size_t)(_t * 512 + tid) * 16,               \
             smem + (loff) + (_t * 512 + tid) * 16);                            \
  } while (0)

__global__ __launch_bounds__(512, 2)
void ffn_fused(const float* __restrict__ x,
               const float* __restrict__ b1,
               const float* __restrict__ b2,
               const char* __restrict__ w1g,
               const char* __restrict__ w2g,
               float* __restrict__ out) {
  extern __shared__ char smem[];
  const int tid = threadIdx.x;
  const int lane = tid & 63, wid = tid >> 6;
  const int l31 = lane & 31, l5 = lane >> 5;
  const int row0 = blockIdx.x * BM;

  // SIMD-balanced roles (SIMD s hosts waves {s, s+4}: one kh0 + one kh1).
  const int p  = wid & 3,  kh = wid >> 2;  // G1: pair (32 rows), k-half
  const int cq = wid & 3,  rh = wid >> 2;  // G2: col-quad (128), row-half (64)
  unsigned* tmpspk = (unsigned*)(smem + H2_0);  // prologue-only

  // ---------------- prologue ----------------
  if (tid < 4) tmpspk[tid] = 0u;
  ISSUE4(W1A_O, w1g);  // w1[0] -> slot 0
  *(float4*)((float*)(smem + B1_O) + tid * 4) = *(const float4*)&b1[tid * 4];

  // x rows -> swizzled f32 slab (W2 slots, free now) -> pair-half regs.
  bf16x8 xr[16];
  for (int r = 0; r < 4; ++r) {
    {
      const float* xg = x + (size_t)(row0 + r * 32) * D;
      float* xs = (float*)(smem + W2A_O);
#pragma unroll
      for (int it = 0; it < 8; ++it) {
        int idx = it * 512 + tid;
        int rl = idx >> 7, col = (idx & 127) * 4;
        float4 v = *(const float4*)(xg + rl * 512 + col);
        *(float4*)(xs + rl * 512 + (col ^ ((rl & 7) << 2))) = v;
      }
    }
    asm volatile("s_waitcnt vmcnt(0) lgkmcnt(0)" ::: "memory");
    __builtin_amdgcn_s_barrier();
    if (p == r) {  // pair r: both k-half waves extract their 16 frags
      const float* xs = (const float*)(smem + W2A_O);
      bool rowany = false;
#pragma unroll
      for (int s = 0; s < 16; ++s) {
        int base = kh * 256 + s * 16 + l5 * 8;
        int c0 = base ^ ((l31 & 7) << 2);
        int c1 = (base + 4) ^ ((l31 & 7) << 2);
        float4 a4 = *(const float4*)(xs + l31 * 512 + c0);
        float4 b4 = *(const float4*)(xs + l31 * 512 + c1);
        rowany = rowany | (fabsf(a4.x) > TH) | (fabsf(a4.y) > TH) |
                 (fabsf(a4.z) > TH) | (fabsf(a4.w) > TH) | (fabsf(b4.x) > TH) |
                 (fabsf(b4.y) > TH) | (fabsf(b4.z) > TH) | (fabsf(b4.w) > TH);
        bf16x8 t;
        t[0] = f2bf(a4.x); t[1] = f2bf(a4.y); t[2] = f2bf(a4.z); t[3] = f2bf(a4.w);
        t[4] = f2bf(b4.x); t[5] = f2bf(b4.y); t[6] = f2bf(b4.z); t[7] = f2bf(b4.w);
        xr[s] = t;
      }
      unsigned long long bl = __ballot(rowany);  // bit l = row (l&31) any
      if (lane == 0) atomicOr(&tmpspk[r], (unsigned)bl | (unsigned)(bl >> 32));
    }
    asm volatile("s_waitcnt lgkmcnt(0)" ::: "memory");
    __builtin_amdgcn_s_barrier();
  }
  // spike masks for this wave's G2 rows (rh*64 .. +63) -> 2 regs
  const unsigned smv0 = tmpspk[rh * 2 + 0];
  const unsigned smv1 = tmpspk[rh * 2 + 1];
  asm volatile("s_waitcnt vmcnt(0) lgkmcnt(0)" ::: "memory");
  __builtin_amdgcn_s_barrier();  // w1[0] landed; H2_0 free

  // "PH2(-1)": pre-issue w1[1] -> slot1, w2[0] -> slot0 (counted, not drained)
  ISSUE4(W1B_O, w1g + 32768);
  ISSUE4(W2A_O, w2g);

  f32x16 oacc[8];
#pragma unroll
  for (int n = 0; n < 8; ++n)
#pragma unroll
    for (int j = 0; j < 16; ++j) oacc[n][j] = 0.f;

  const float* b1s = (const float*)(smem + B1_O);

  // ------------- main loop: 64 chunks x {PH1 (fused compute), PH2} -------
  // Queue (oldest->newest) at PH1(i) entry: w1[i](4), w2[i-1](4), w1[i+1](4),
  // w2[i](4).  Entry wait vmcnt(8) drains exactly {w1[i], w2[i-1]} = what PH1
  // consumes.  NO other vmcnt in the loop; all issues are in PH2:
  //   PH2(i): issue w1[i+2]->slot i&1 (freed by G1(i)),
  //           issue w2[i+1]->slot (i+1)&1 (freed by G2(i-1)).
  // PH1 = G2(i-1) + G1(i) in ONE wall-free region -> scheduler interleaves
  // G1's ds_reads under G2's MFMAs and vice versa.
#pragma unroll 1
  for (int i = 0; i < NC; ++i) {
    const int sl = i & 1;
    f32x16 hacc;

    // ---- PH1 ----
    if (i < NC - 1) asm volatile("s_waitcnt vmcnt(8)" ::: "memory");
    else            asm volatile("s_waitcnt vmcnt(4)" ::: "memory");

    __builtin_amdgcn_s_setprio(1);
    if (i > 0) {  // G2 on chunk i-1
      const int js = (i - 1) & 1;
      const char* h2r  = smem + (js ? H2_1 : H2_0);
      const char* w2rd = smem + (js ? W2B_O : W2A_O);
#pragma unroll
      for (int ks = 0; ks < 2; ++ks) {
        bf16x8 hA0 = *(const bf16x8*)(h2r + ((2 * ks + l5) * 128 + rh * 64 + l31) * 16);
        bf16x8 hA1 = *(const bf16x8*)(h2r + ((2 * ks + l5) * 128 + rh * 64 + 32 + l31) * 16);
#pragma unroll
        for (int n = 0; n < 4; ++n) {
          bf16x8 wf = *(const bf16x8*)(w2rd + ks * 16384 + (cq * 4 + n) * 1024 + lane * 16);
          oacc[n]     = MFMA32(hA0, wf, oacc[n]);
          oacc[4 + n] = MFMA32(hA1, wf, oacc[4 + n]);
        }
      }
    }
    {  // G1 on chunk i (independent of G2 above -> free to interleave)
      const char* w1slot = smem + (sl ? W1B_O : W1A_O);
#pragma unroll
      for (int j = 0; j < 16; ++j) hacc[j] = 0.f;
#pragma unroll
      for (int s = 0; s < 16; ++s) {
        bf16x8 wf = *(const bf16x8*)(w1slot + (kh * 16 + s) * 1024 + lane * 16);
        hacc = MFMA32(wf, xr[s], hacc);
      }
    }
    __builtin_amdgcn_s_setprio(0);
    if (kh) {  // odd k-half: bf16-pack partial -> hp
      u32x4 pk0, pk1;
#pragma unroll
      for (int t = 0; t < 4; ++t) {
        pk0[t] = (unsigned)(unsigned short)f2bf(hacc[2 * t]) |
                 ((unsigned)(unsigned short)f2bf(hacc[2 * t + 1]) << 16);
        pk1[t] = (unsigned)(unsigned short)f2bf(hacc[8 + 2 * t]) |
                 ((unsigned)(unsigned short)f2bf(hacc[8 + 2 * t + 1]) << 16);
      }
      *(u32x4*)(smem + HP_O + p * 2048 + lane * 32) = pk0;
      *(u32x4*)(smem + HP_O + p * 2048 + lane * 32 + 16) = pk1;
    }
    asm volatile("s_waitcnt lgkmcnt(0)" ::: "memory");
    __builtin_amdgcn_s_barrier();  // end-PH1

    // ---- PH2 ----
    if (!kh) {  // even k-half: combine + bias + relu + pack -> h2[sl]
      const char* hp = smem + HP_O + p * 2048;
      u32x4 q0 = *(const u32x4*)(hp + lane * 32);
      u32x4 q1 = *(const u32x4*)(hp + lane * 32 + 16);
#pragma unroll
      for (int t = 0; t < 4; ++t) {
        hacc[2 * t]     += __uint_as_float(q0[t] << 16);
        hacc[2 * t + 1] += __uint_as_float(q0[t] & 0xffff0000u);
        hacc[8 + 2 * t]     += __uint_as_float(q1[t] << 16);
        hacc[8 + 2 * t + 1] += __uint_as_float(q1[t] & 0xffff0000u);
      }
      char* h2w = smem + (sl ? H2_1 : H2_0);
#pragma unroll
      for (int q = 0; q < 4; ++q) {
        float4 bv = *(const float4*)&b1s[i * 32 + q * 8 + l5 * 4];
        short4 pk;
        pk.x = f2bf(fmaxf(hacc[4 * q + 0] + bv.x, 0.f));
        pk.y = f2bf(fmaxf(hacc[4 * q + 1] + bv.y, 0.f));
        pk.z = f2bf(fmaxf(hacc[4 * q + 2] + bv.z, 0.f));
        pk.w = f2bf(fmaxf(hacc[4 * q + 3] + bv.w, 0.f));
        *(short4*)(h2w + q * 2048 + (p * 32 + l31) * 16 + l5 * 8) = pk;
      }
    }
    if (i + 2 < NC) ISSUE4(sl ? W1B_O : W1A_O, w1g + (size_t)(i + 2) * 32768);
    if (i + 1 < NC) ISSUE4(((i + 1) & 1) ? W2B_O : W2A_O,
                           w2g + (size_t)(i + 1) * 32768);
    asm volatile("s_waitcnt lgkmcnt(0)" ::: "memory");
    __builtin_amdgcn_s_barrier();  // end-PH2 (h2[i] visible)
  }

  // ---------------- epilogue: G2 chunk 63 + store ----------------
  asm volatile("s_waitcnt vmcnt(0)" ::: "memory");  // w2[63] landed
  {
    const char* h2r  = smem + H2_1;   // 63 & 1 = 1
    const char* w2rd = smem + W2B_O;
    __builtin_amdgcn_s_setprio(1);
#pragma unroll
    for (int ks = 0; ks < 2; ++ks) {
      bf16x8 hA0 = *(const bf16x8*)(h2r + ((2 * ks + l5) * 128 + rh * 64 + l31) * 16);
      bf16x8 hA1 = *(const bf16x8*)(h2r + ((2 * ks + l5) * 128 + rh * 64 + 32 + l31) * 16);
#pragma unroll
      for (int n = 0; n < 4; ++n) {
        bf16x8 wf = *(const bf16x8*)(w2rd + ks * 16384 + (cq * 4 + n) * 1024 + lane * 16);
        oacc[n]     = MFMA32(hA0, wf, oacc[n]);
        oacc[4 + n] = MFMA32(hA1, wf, oacc[4 + n]);
      }
    }
    __builtin_amdgcn_s_setprio(0);
  }
#pragma unroll
  for (int rfi = 0; rfi < 2; ++rfi) {
    unsigned m = rfi ? smv1 : smv0;
#pragma unroll
    for (int n = 0; n < 4; ++n) {
      int dcol = cq * 128 + n * 32 + l31;
      float bias = b2[dcol];
      f32x16 acc = oacc[rfi * 4 + n];
#pragma unroll
      for (int r = 0; r < 16; ++r) {
        int rbit = (r & 3) + 8 * (r >> 2) + 4 * l5;
        int row = rh * 64 + rfi * 32 + rbit;
        float v = acc[r] + bias;
        out[(size_t)(row0 + row) * D + dcol] = ((m >> rbit) & 1u) ? v : 0.f;
      }
    }
  }
}

extern "C" void kernel_launch(void* const* d_in, const int* in_sizes, int n_in,
                              void* d_out, int out_size, void* d_ws, size_t ws_size,
                              hipStream_t stream) {
  const float* x  = (const float*)d_in[0];
  const float* w1 = (const float*)d_in[1];
  const float* b1 = (const float*)d_in[2];
  const float* w2 = (const float*)d_in[3];
  const float* b2 = (const float*)d_in[4];
  float* out = (float*)d_out;

  short* w1staged = (short*)d_ws;               // 2 MB
  short* w2staged = w1staged + (size_t)D * F;   // 2 MB

  prep_weights<<<1024, 256, 0, stream>>>(w1, w2, w1staged, w2staged);

  (void)hipFuncSetAttribute((const void*)ffn_fused,
                            hipFuncAttributeMaxDynamicSharedMemorySize, LDS_TOTAL);
  int M = out_size / D;  // 32768
  ffn_fused<<<M / BM, 512, LDS_TOTAL, stream>>>(x, b1, b2, (const char*)w1staged,
                                                (const char*)w2staged, out);
}